// Round 15
// baseline (452.104 us; speedup 1.0000x reference)
//
#include <hip/hip_runtime.h>
#include <hip/hip_fp8.h>

typedef __bf16 bf16x8 __attribute__((ext_vector_type(8)));
typedef float  f32x4  __attribute__((ext_vector_type(4)));

#define NMEM_   65536
#define NCHUNK_ 16
#define NKC_    (NMEM_/NCHUNK_)   /* 4096 keys per chunk */
#define XPD_    160               /* padded DIN (133 -> 160) */

/* workspace byte offsets (all 4KB-aligned) */
#define WS_KB    ((size_t)0)           /* keys FP8 SWIZZLED [65536][512B] 33.5MB */
#define WS_VT    ((size_t)67108864)    /* vals^T FP8 x16 [512][65536B] 33.5MB */
#define WS_KNRM  ((size_t)134217728)   /* ||k||^2 f32 [65536]       */
#define WS_QB    ((size_t)134479872)   /* cue FP8 linear [1024][512B]   */
#define WS_QQ    ((size_t)135528448)   /* ||q||^2 f32 [1024]        */
#define WS_OP    ((size_t)135532544)   /* O partials f32 [16][32][512][32] 33.6MB */
#define WS_LP    ((size_t)169086976)   /* L partials f32 [16][1024]  */
#define WS_MT    ((size_t)169152512)   /* m_t f32 [1024][512]        */
#define WS_XP    ((size_t)171249664)   /* x_t bf16 padded [1024][160]*/
#define WS_HB    ((size_t)171577344)   /* h0 bf16 [1024][512]        */
#define WS_WIHP  ((size_t)172625920)   /* w_ih bf16 padded [2560][160]*/
#define WS_WHHB  ((size_t)173445120)   /* w_hh bf16 [2560][512]      */
#define WS_Z     ((size_t)176066560)   /* z f32 [1024][2560]         */

/* output float offsets */
#define OUT_LOG   0
#define OUT_VAL   4096
#define OUT_H     5120
#define OUT_C     529408
#define OUT_FEATS 1053696

__device__ __forceinline__ void gload16(const void* g, void* l) {
    __builtin_amdgcn_global_load_lds(
        (const __attribute__((address_space(1))) void*)g,
        (__attribute__((address_space(3))) void*)l, 16, 0, 0);
}

__device__ __forceinline__ unsigned char to_fp8(float f) {
    __hip_fp8_e4m3 v(f);
    return *(unsigned char*)&v;
}

/* 8 packed fp8 e4m3 -> bf16x8. HW cvt path when available; exact bit-trick
 * fallback (denormal-correct: f32 denormal x 2^120 is exact). */
__device__ __forceinline__ bf16x8 fp8x8_bf16(long v) {
    union { long l; unsigned int w[2]; } u; u.l = v;
    bf16x8 o;
#if __has_builtin(__builtin_amdgcn_cvt_f32_fp8)
    #pragma unroll
    for (int h = 0; h < 2; h++) {
        o[h*4+0] = (__bf16)__builtin_amdgcn_cvt_f32_fp8(u.w[h], 0);
        o[h*4+1] = (__bf16)__builtin_amdgcn_cvt_f32_fp8(u.w[h], 1);
        o[h*4+2] = (__bf16)__builtin_amdgcn_cvt_f32_fp8(u.w[h], 2);
        o[h*4+3] = (__bf16)__builtin_amdgcn_cvt_f32_fp8(u.w[h], 3);
    }
#else
    #pragma unroll
    for (int i = 0; i < 8; i++) {
        unsigned int b = (u.w[i>>2] >> ((i & 3) * 8)) & 0xffu;
        unsigned int t = ((b & 0x7fu) << 20) | ((b & 0x80u) << 24);
        float f; __builtin_memcpy(&f, &t, 4);
        o[i] = (__bf16)(f * 0x1p120f);
    }
#endif
    return o;
}

/* ---------------- encoder MLP + x_t assembly ---------------- */
__global__ __launch_bounds__(256) void enc_kernel(
    const float* __restrict__ obs, const float* __restrict__ pa, const float* __restrict__ pr,
    const float* __restrict__ w1, const float* __restrict__ b1,
    const float* __restrict__ w2, const float* __restrict__ b2,
    float* __restrict__ feats_out, __bf16* __restrict__ xp)
{
    __shared__ float W1s[64*9];
    __shared__ float B1s[64];
    __shared__ float W2s[128*64];
    __shared__ float B2s[128];
    int t = threadIdx.x;
    for (int i = t; i < 64*9;   i += 256) W1s[i] = w1[i];
    for (int i = t; i < 64;     i += 256) B1s[i] = b1[i];
    for (int i = t; i < 128*64; i += 256) W2s[i] = w2[i];
    for (int i = t; i < 128;    i += 256) B2s[i] = b2[i];
    __syncthreads();
    int row = blockIdx.x * 256 + t;
    float ob[9];
    #pragma unroll
    for (int j = 0; j < 9; j++) ob[j] = obs[row*9 + j];
    float h1[64];
    #pragma unroll 4
    for (int i = 0; i < 64; i++) {
        float a = B1s[i];
        #pragma unroll
        for (int j = 0; j < 9; j++) a += ob[j] * W1s[i*9 + j];
        h1[i] = fmaxf(a, 0.f);
    }
    for (int j = 0; j < 128; j += 4) {
        float a0 = B2s[j], a1 = B2s[j+1], a2 = B2s[j+2], a3 = B2s[j+3];
        for (int i = 0; i < 64; i++) {
            float h = h1[i];
            a0 += h * W2s[(j+0)*64 + i];
            a1 += h * W2s[(j+1)*64 + i];
            a2 += h * W2s[(j+2)*64 + i];
            a3 += h * W2s[(j+3)*64 + i];
        }
        a0 = fmaxf(a0,0.f); a1 = fmaxf(a1,0.f); a2 = fmaxf(a2,0.f); a3 = fmaxf(a3,0.f);
        feats_out[row*128 + j+0] = a0; feats_out[row*128 + j+1] = a1;
        feats_out[row*128 + j+2] = a2; feats_out[row*128 + j+3] = a3;
        xp[row*XPD_ + j+0] = (__bf16)a0; xp[row*XPD_ + j+1] = (__bf16)a1;
        xp[row*XPD_ + j+2] = (__bf16)a2; xp[row*XPD_ + j+3] = (__bf16)a3;
    }
    #pragma unroll
    for (int k = 0; k < 4; k++) xp[row*XPD_ + 128 + k] = (__bf16)pa[row*4 + k];
    xp[row*XPD_ + 132] = (__bf16)pr[row];
    #pragma unroll
    for (int c = 133; c < 160; c++) xp[row*XPD_ + c] = (__bf16)0.f;
}

/* ---------------- fused conversion kernel ----------------
 * keys/cue -> FP8 e4m3; vals^T -> FP8 e4m3 scaled x16 (descaled in combine).
 * keys swizzled for 8B ds_reads: byte c of row at c ^ ((row&15)<<3). */
#define CV_KEYS 16384
#define CV_CUE  (CV_KEYS + 256)
#define CV_VT   (CV_CUE + 8192)
#define CM_N1 (2560*512)
#define CM_N2 (1024*512)
#define CM_N3 (2560*160)
#define CV_ALL  (CV_VT + (CM_N1 + CM_N2 + CM_N3 + 255)/256)

__global__ __launch_bounds__(256) void conv_all(
    const float* __restrict__ keys, const float* __restrict__ cue,
    const float* __restrict__ vals,
    const float* __restrict__ whh, const float* __restrict__ h0,
    const float* __restrict__ wih,
    unsigned char* __restrict__ Kb, float* __restrict__ knrm,
    unsigned char* __restrict__ Qb, float* __restrict__ qq,
    unsigned char* __restrict__ Vt,
    __bf16* __restrict__ Whhb, __bf16* __restrict__ Hb, __bf16* __restrict__ Wihp)
{
    int bid = blockIdx.x;
    if (bid < CV_CUE) {
        const float* src; unsigned char* dst; float* nrm; int swz, rbase;
        if (bid < CV_KEYS) { src = keys; dst = Kb; nrm = knrm; swz = 1; rbase = bid*4; }
        else               { src = cue;  dst = Qb; nrm = qq;  swz = 0; rbase = (bid-CV_KEYS)*4; }
        int row  = rbase + (threadIdx.x >> 6);
        int lane = threadIdx.x & 63;
        const float* s = src + (size_t)row * 512 + lane * 8;
        float4 v0 = *(const float4*)s;
        float4 v1 = *(const float4*)(s + 4);
        float ss = v0.x*v0.x + v0.y*v0.y + v0.z*v0.z + v0.w*v0.w
                 + v1.x*v1.x + v1.y*v1.y + v1.z*v1.z + v1.w*v1.w;
        union { unsigned char b[8]; long v; } pk;
        pk.b[0] = to_fp8(v0.x); pk.b[1] = to_fp8(v0.y);
        pk.b[2] = to_fp8(v0.z); pk.b[3] = to_fp8(v0.w);
        pk.b[4] = to_fp8(v1.x); pk.b[5] = to_fp8(v1.y);
        pk.b[6] = to_fp8(v1.z); pk.b[7] = to_fp8(v1.w);
        int c = lane * 8;
        int addr = swz ? (c ^ ((row & 15) << 3)) : c;
        *(long*)(dst + (size_t)row * 512 + addr) = pk.v;
        #pragma unroll
        for (int m = 1; m < 64; m <<= 1) ss += __shfl_xor(ss, m, 64);
        if (lane == 0) nrm[row] = ss;
        return;
    }
    if (bid < CV_VT) {
        __shared__ float Ls[64*65];
        int local = bid - CV_CUE;
        int k0 = (local & 1023) * 64, d0 = (local >> 10) * 64;
        int rr = threadIdx.x >> 6, cc = threadIdx.x & 63;
        #pragma unroll
        for (int i = 0; i < 16; i++) {
            int row = i*4 + rr;
            Ls[row*65 + cc] = vals[(size_t)(k0 + row) * 512 + d0 + cc];
        }
        __syncthreads();
        #pragma unroll
        for (int i = 0; i < 16; i++) {
            int drow = i*4 + rr;
            Vt[(size_t)(d0 + drow) * 65536 + k0 + cc] = to_fp8(Ls[cc*65 + drow] * 16.f);
        }
        return;
    }
    {
        int i = (bid - CV_VT) * 256 + threadIdx.x;
        if (i < CM_N1) { Whhb[i] = (__bf16)whh[i]; return; }
        i -= CM_N1;
        if (i < CM_N2) { Hb[i] = (__bf16)h0[i]; return; }
        i -= CM_N2;
        if (i < CM_N3) {
            int r = i / 160, c = i - r * 160;
            Wihp[i] = (c < 133) ? (__bf16)wih[r*133 + c] : (__bf16)0.f;
        }
    }
}

/* ---------------- DND flash kernel v15: 2 barrier domains / CU ----------
 * = v14's schedule (QK(t) || PV(t-1), 1 barrier/tile, counted vmcnt, no
 * vmcnt(0) in loop) re-tiled: 256 thr / 4 waves / 32 q-rows per block,
 * grid 512 = 16 chunks x 32 q-tiles, KT=64 kept (64 tiles). LDS 74KB ->
 * TWO blocks co-resident per CU with independent barriers: one block's
 * MFMA phase overlaps the other's VALU/wait phase (the uniform-25%
 * lockstep was the diagnosed floor).  fp8 K (LDS-staged, swizzled),
 * fp8 V x16 (reg-loaded, converted), bf16 PV.  Per-wave work identical
 * to v14: QK 32 MFMA + PV 32 MFMA per tile.  acc in AGPRs (v7 evidence),
 * arch VGPR ~100 -> no 128-cliff. */
__global__ __launch_bounds__(256) __attribute__((amdgpu_waves_per_eu(2)))
void flash_kernel(
    const unsigned char* __restrict__ Kb, const unsigned char* __restrict__ Vt,
    const unsigned char* __restrict__ Qb, const float* __restrict__ qq,
    const float* __restrict__ knrm,
    float* __restrict__ Opart, float* __restrict__ Lpart)
{
    extern __shared__ char smem[];
    char*  KL  = smem;                       /* [2][32KB] fp8 K tiles (swizzled)*/
    char*  Plb = smem + 65536;               /* [2][32 q][128B] P dbuf swizzled */
    float* Lb  = (float*)(smem + 73728);     /* [32 q][2 wk]                    */

    const int tid = threadIdx.x, lane = tid & 63, w = tid >> 6;
    const int wq = w >> 1, wk = w & 1;
    const int lr = lane & 15, lq = lane >> 4;
    const int chunk = blockIdx.x & 15, qt = blockIdx.x >> 4;
    const int q0 = qt * 32, key0 = chunk * NKC_;

    /* Q fp8 fragments in registers: row=lr, 8 k-bytes at ks*32+lq*8. 32 VGPR */
    long qA[16];
    #pragma unroll
    for (int ks = 0; ks < 16; ks++)
        qA[ks] = *(const long*)(Qb + (size_t)(q0 + wq*16 + lr)*512 + ks*32 + lq*8);
    float qq4[4];
    #pragma unroll
    for (int r = 0; r < 4; r++)
        qq4[r] = qq[q0 + wq*16 + lq*4 + r];

    const float*         knp  = knrm + key0 + wk*32 + lr;
    const unsigned char* vrow = Vt + (size_t)(w*128 + lr)*65536 + key0 + lq*8;
    const char*          kg   = (const char*)Kb + (size_t)key0 * 512;

    /* prologue: stage fp8 K tile 0 (32KB = 8 x 16B/thread), drain, barrier */
    #pragma unroll
    for (int r = 0; r < 8; ++r)
        gload16(kg + r*4096 + tid*16, KL + r*4096 + tid*16);
    asm volatile("s_waitcnt vmcnt(0)" ::: "memory");
    __builtin_amdgcn_s_barrier();

    f32x4 oacc[8][2] = {};            /* O^T frags: [mf d][f2 q] = 64 acc regs */
    float lsum[4] = {};
    int cur = 0;
    const int kxor = lr << 3;

    #pragma unroll 1
    for (int t = 0; t < 64; ++t) {
        /* ---- issues: kn(2), V-raw(16) for tile t-1, stage-next(8) = 26 vmem ---- */
        float kn0 = knp[t*64];
        float kn1 = knp[t*64 + 16];
        const unsigned char* vb = vrow + ((t + 63) & 63) * 64;   /* V of tile t-1 */
        long vr[2][8];
        #pragma unroll
        for (int k2 = 0; k2 < 2; ++k2)
            #pragma unroll
            for (int mf = 0; mf < 8; ++mf)
                vr[k2][mf] = *(const long*)(vb + k2*32 + (size_t)mf*1048576);
        {   /* stage tile (t+1)&63 (wrap keeps vmcnt count uniform) */
            const char* src = kg + (size_t)((t+1)&63)*32768;
            char* dst = KL + (cur^1)*32768;
            #pragma unroll
            for (int r = 0; r < 8; ++r)
                gload16(src + r*4096 + tid*16, dst + r*4096 + tid*16);
        }
        /* own stage(t) done (26 = ops issued this iter) + own SM(t-1)
         * ds_writes drained; barrier makes it true block-wide.
         * stage(t+1)/vr/kn remain in flight. */
        asm volatile("s_waitcnt vmcnt(26) lgkmcnt(0)" ::: "memory");
        __builtin_amdgcn_sched_barrier(0);
        __builtin_amdgcn_s_barrier();
        /* ---- QK(t): S[16q x 32k], contraction 512, fp8 ---- */
        const char* kl = KL + cur*32768 + (wk*32 + lr)*512;
        f32x4 s0 = {0.f,0.f,0.f,0.f}, s1 = {0.f,0.f,0.f,0.f};
        __builtin_amdgcn_s_setprio(1);
        #pragma unroll
        for (int ks = 0; ks < 16; ++ks) {
            int off = (ks*32 + lq*8) ^ kxor;
            long kf0 = *(const long*)(kl + off);
            long kf1 = *(const long*)(kl + 8192 + off);
            s0 = __builtin_amdgcn_mfma_f32_16x16x32_fp8_fp8(qA[ks], kf0, s0, 0, 0, 0);
            s1 = __builtin_amdgcn_mfma_f32_16x16x32_fp8_fp8(qA[ks], kf1, s1, 0, 0, 0);
        }
        /* ---- PV(t-1): convert V fp8->bf16, O^T += V^T * P ---- */
        if (t) {
            const char* pb_ = Plb + ((t+1)&1)*4096;
            #pragma unroll
            for (int k2 = 0; k2 < 2; ++k2) {
                bf16x8 vc[8];
                #pragma unroll
                for (int mf = 0; mf < 8; ++mf)
                    vc[mf] = fp8x8_bf16(vr[k2][mf]);
                #pragma unroll
                for (int f2 = 0; f2 < 2; ++f2) {
                    bf16x8 pf = *(const bf16x8*)(pb_ + (f2*16 + lr)*128
                                 + ((k2*64 + lq*16) ^ ((lr & 7) << 4)));
                    #pragma unroll
                    for (int mf = 0; mf < 8; ++mf)
                        oacc[mf][f2] = __builtin_amdgcn_mfma_f32_16x16x32_bf16(
                            vc[mf], pf, oacc[mf][f2], 0, 0, 0);
                }
            }
        }
        __builtin_amdgcn_s_setprio(0);
        /* ---- SM(t): softmax numerator + P[t&1] write (swizzled) ---- */
        char* pw = Plb + (t&1)*4096;
        #pragma unroll
        for (int r = 0; r < 4; ++r) {
            float d20 = fmaxf(qq4[r] + kn0 - 2.f*s0[r], 1e-12f);
            float d21 = fmaxf(qq4[r] + kn1 - 2.f*s1[r], 1e-12f);
            float p0 = __expf(-__builtin_amdgcn_sqrtf(d20));
            float p1 = __expf(-__builtin_amdgcn_sqrtf(d21));
            lsum[r] += p0 + p1;
            int row_ = wq*16 + lq*4 + r;
            int sw = (row_ & 7) << 4;
            *(__bf16*)(pw + row_*128 + (((wk*32 + lr)*2     ) ^ sw)) = (__bf16)p0;
            *(__bf16*)(pw + row_*128 + (((wk*32 + lr)*2 + 32) ^ sw)) = (__bf16)p1;
        }
        cur ^= 1;
    }

    /* ---- epilogue: PV(63), P buf 1 ---- */
    {
        const unsigned char* vb = vrow + 63*64;
        long vr[2][8];
        #pragma unroll
        for (int k2 = 0; k2 < 2; ++k2)
            #pragma unroll
            for (int mf = 0; mf < 8; ++mf)
                vr[k2][mf] = *(const long*)(vb + k2*32 + (size_t)mf*1048576);
        asm volatile("s_waitcnt lgkmcnt(0)" ::: "memory");
        __builtin_amdgcn_sched_barrier(0);
        __builtin_amdgcn_s_barrier();              /* P[1] ready block-wide */
        const char* pb_ = Plb + 4096;
        #pragma unroll
        for (int k2 = 0; k2 < 2; ++k2) {
            bf16x8 vc[8];
            #pragma unroll
            for (int mf = 0; mf < 8; ++mf)
                vc[mf] = fp8x8_bf16(vr[k2][mf]);
            #pragma unroll
            for (int f2 = 0; f2 < 2; ++f2) {
                bf16x8 pf = *(const bf16x8*)(pb_ + (f2*16 + lr)*128
                             + ((k2*64 + lq*16) ^ ((lr & 7) << 4)));
                #pragma unroll
                for (int mf = 0; mf < 8; ++mf)
                    oacc[mf][f2] = __builtin_amdgcn_mfma_f32_16x16x32_bf16(
                        vc[mf], pf, oacc[mf][f2], 0, 0, 0);
            }
        }
    }
    asm volatile("s_waitcnt vmcnt(0)" ::: "memory");  /* drain wrap-stage DMA */

    /* O partials: layout [(chunk*32+qt)*512 + d][32 ql] */
    const size_t obase = (size_t)((chunk*32 + qt)*512) * 32;
    #pragma unroll
    for (int mf = 0; mf < 8; ++mf)
        #pragma unroll
        for (int f2 = 0; f2 < 2; ++f2)
            #pragma unroll
            for (int r = 0; r < 4; ++r) {
                int d = w*128 + mf*16 + lq*4 + r;
                Opart[obase + (size_t)d*32 + f2*16 + lr] = oacc[mf][f2][r];
            }
    #pragma unroll
    for (int r = 0; r < 4; ++r) {
        float s = lsum[r];
        s += __shfl_xor(s, 1, 64); s += __shfl_xor(s, 2, 64);
        s += __shfl_xor(s, 4, 64); s += __shfl_xor(s, 8, 64);
        if (lr == 0) Lb[(wq*16 + lq*4 + r)*2 + wk] = s;
    }
    __syncthreads();
    if (tid < 32)
        Lpart[chunk*1024 + q0 + tid] = Lb[tid*2] + Lb[tid*2 + 1];
}

/* ---------------- combine split-K partials -> m_t ----------------
 * Opart [16 chunks][32 qt][512 d][32 q]; grid (32 qt, 8 db), 256 thr.
 * Ls includes the 1/16 descale of the fp8 V encoding. */
__global__ __launch_bounds__(256) void combine_kernel(
    const float* __restrict__ Opart, const float* __restrict__ Lpart,
    float* __restrict__ mt)
{
    __shared__ float Ts[64*33];
    __shared__ float Ls[32];
    int qt = blockIdx.x, db = blockIdx.y * 64, t = threadIdx.x;
    float acc[8] = {};
    for (int c = 0; c < NCHUNK_; c++) {
        size_t base = (size_t)((c*32 + qt)*512 + db) * 32;
        #pragma unroll
        for (int i = 0; i < 8; i++) acc[i] += Opart[base + t + 256*i];
    }
    if (t < 32) {
        float s = 0.f;
        for (int c = 0; c < NCHUNK_; c++) s += Lpart[c*1024 + qt*32 + t];
        Ls[t] = 1.f / (s * 16.f);
    }
    #pragma unroll
    for (int i = 0; i < 8; i++) {
        int idx = t + 256*i;                 /* d = idx>>5 (0..63), q = idx&31 */
        Ts[(idx >> 5)*33 + (idx & 31)] = acc[i];
    }
    __syncthreads();
    #pragma unroll
    for (int i = 0; i < 8; i++) {
        int widx = t + 256*i;                /* q = widx>>6 (0..31), d = widx&63 */
        int q = widx >> 6, dloc = widx & 63;
        mt[(size_t)(qt*32 + q)*512 + db + dloc] = Ts[dloc*33 + q] * Ls[q];
    }
}

/* ---------------- LSTM pre-activation GEMM: z = Xp@Wih^T + H@Whh^T + b ---------------- */
__global__ __launch_bounds__(256) void lstm_gemm(
    const __bf16* __restrict__ X,  const __bf16* __restrict__ Wx,
    const __bf16* __restrict__ Hb, const __bf16* __restrict__ Wh,
    const float* __restrict__ bi,  const float* __restrict__ bh,
    float* __restrict__ z)
{
    int tid = threadIdx.x, lane = tid & 63, w = tid >> 6;
    int wr = w >> 1, wc = w & 1;
    int lr = lane & 15, lq = lane >> 4;
    int q0 = blockIdx.x * 64, n0 = blockIdx.y * 64;
    f32x4 acc00 = {}, acc01 = {}, acc10 = {}, acc11 = {};
    #pragma unroll
    for (int ks = 0; ks < 5; ks++) {                       /* X part, K=160 */
        bf16x8 a0 = *(const bf16x8*)(X  + (size_t)(q0 + wr*32      + lr)*XPD_ + ks*32 + lq*8);
        bf16x8 a1 = *(const bf16x8*)(X  + (size_t)(q0 + wr*32 + 16 + lr)*XPD_ + ks*32 + lq*8);
        bf16x8 b0 = *(const bf16x8*)(Wx + (size_t)(n0 + wc*32      + lr)*XPD_ + ks*32 + lq*8);
        bf16x8 b1 = *(const bf16x8*)(Wx + (size_t)(n0 + wc*32 + 16 + lr)*XPD_ + ks*32 + lq*8);
        acc00 = __builtin_amdgcn_mfma_f32_16x16x32_bf16(a0, b0, acc00, 0,0,0);
        acc01 = __builtin_amdgcn_mfma_f32_16x16x32_bf16(a0, b1, acc01, 0,0,0);
        acc10 = __builtin_amdgcn_mfma_f32_16x16x32_bf16(a1, b0, acc10, 0,0,0);
        acc11 = __builtin_amdgcn_mfma_f32_16x16x32_bf16(a1, b1, acc11, 0,0,0);
    }
    #pragma unroll
    for (int ks = 0; ks < 16; ks++) {                      /* H part, K=512 */
        bf16x8 a0 = *(const bf16x8*)(Hb + (size_t)(q0 + wr*32      + lr)*512 + ks*32 + lq*8);
        bf16x8 a1 = *(const bf16x8*)(Hb + (size_t)(q0 + wr*32 + 16 + lr)*512 + ks*32 + lq*8);
        bf16x8 b0 = *(const bf16x8*)(Wh + (size_t)(n0 + wc*32      + lr)*512 + ks*32 + lq*8);
        bf16x8 b1 = *(const bf16x8*)(Wh + (size_t)(n0 + wc*32 + 16 + lr)*512 + ks*32 + lq*8);
        acc00 = __builtin_amdgcn_mfma_f32_16x16x32_bf16(a0, b0, acc00, 0,0,0);
        acc01 = __builtin_amdgcn_mfma_f32_16x16x32_bf16(a0, b1, acc01, 0,0,0);
        acc10 = __builtin_amdgcn_mfma_f32_16x16x32_bf16(a1, b0, acc10, 0,0,0);
        acc11 = __builtin_amdgcn_mfma_f32_16x16x32_bf16(a1, b1, acc11, 0,0,0);
    }
    int nA = n0 + wc*32 + lr, nB = nA + 16;
    float biasA = bi[nA] + bh[nA], biasB = bi[nB] + bh[nB];
    #pragma unroll
    for (int r = 0; r < 4; r++) {
        int qa = q0 + wr*32 + lq*4 + r, qb = qa + 16;
        z[(size_t)qa*2560 + nA] = acc00[r] + biasA;
        z[(size_t)qa*2560 + nB] = acc01[r] + biasB;
        z[(size_t)qb*2560 + nA] = acc10[r] + biasA;
        z[(size_t)qb*2560 + nB] = acc11[r] + biasB;
    }
}

/* ---------------- gates + heads ---------------- */
__global__ __launch_bounds__(256) void gates_kernel(
    const float* __restrict__ z,  const float* __restrict__ c0, const float* __restrict__ mt,
    const float* __restrict__ aw, const float* __restrict__ ab,
    const float* __restrict__ cw, const float* __restrict__ cb,
    float* __restrict__ out)
{
    __shared__ float hrow[512];
    __shared__ float red[256];
    int q = blockIdx.x, t = threadIdx.x;
    const float* zq = z + (size_t)q * 2560;
    for (int d = t; d < 512; d += 256) {
        float zi = zq[d], zf = zq[512 + d], zg = zq[1024 + d], zo = zq[1536 + d], zr = zq[2048 + d];
        float ig = 1.f / (1.f + __expf(-zi));
        float fg = 1.f / (1.f + __expf(-zf));
        float gg = tanhf(zg);
        float og = 1.f / (1.f + __expf(-zo));
        float rg = 1.f / (1.f + __expf(-zr));
        float cn = fg * c0[(size_t)q*512 + d] + ig * gg + rg * mt[(size_t)q*512 + d];
        float hn = og * tanhf(cn);
        out[OUT_H + (size_t)q*512 + d] = hn;
        out[OUT_C + (size_t)q*512 + d] = cn;
        hrow[d] = hn;
    }
    __syncthreads();
    for (int o = 0; o < 5; o++) {
        const float* wv = (o < 4) ? (aw + o*512) : cw;
        float p = 0.f;
        for (int d = t; d < 512; d += 256) p += hrow[d] * wv[d];
        red[t] = p;
        __syncthreads();
        for (int s = 128; s > 0; s >>= 1) {
            if (t < s) red[t] += red[t + s];
            __syncthreads();
        }
        if (t == 0) {
            float v = red[0] + ((o < 4) ? ab[o] : cb[0]);
            if (o < 4) out[OUT_LOG + q*4 + o] = v;
            else       out[OUT_VAL + q] = v;
        }
        __syncthreads();
    }
}

extern "C" void kernel_launch(void* const* d_in, const int* in_sizes, int n_in,
                              void* d_out, int out_size, void* d_ws, size_t ws_size,
                              hipStream_t stream) {
    (void)in_sizes; (void)n_in; (void)out_size; (void)ws_size;
    const float* obs   = (const float*)d_in[0];
    const float* pa    = (const float*)d_in[1];
    const float* pr    = (const float*)d_in[2];
    const float* h0    = (const float*)d_in[3];
    const float* c0    = (const float*)d_in[4];
    const float* cue   = (const float*)d_in[5];
    const float* ew1   = (const float*)d_in[6];
    const float* eb1   = (const float*)d_in[7];
    const float* ew2   = (const float*)d_in[8];
    const float* eb2   = (const float*)d_in[9];
    const float* w_ih  = (const float*)d_in[10];
    const float* w_hh  = (const float*)d_in[11];
    const float* b_ih  = (const float*)d_in[12];
    const float* b_hh  = (const float*)d_in[13];
    const float* aw    = (const float*)d_in[14];
    const float* ab    = (const float*)d_in[15];
    const float* cw    = (const float*)d_in[16];
    const float* cb    = (const float*)d_in[17];
    const float* keys  = (const float*)d_in[18];
    const float* vals  = (const float*)d_in[19];

    char* ws = (char*)d_ws;
    unsigned char* Kb = (unsigned char*)(ws + WS_KB);
    unsigned char* Vt = (unsigned char*)(ws + WS_VT);
    float*  knrm  = (float*) (ws + WS_KNRM);
    unsigned char* Qb = (unsigned char*)(ws + WS_QB);
    float*  qq    = (float*) (ws + WS_QQ);
    float*  Opart = (float*) (ws + WS_OP);
    float*  Lpart = (float*) (ws + WS_LP);
    float*  mt    = (float*) (ws + WS_MT);
    __bf16* Xp    = (__bf16*)(ws + WS_XP);
    __bf16* Hb    = (__bf16*)(ws + WS_HB);
    __bf16* Wihp  = (__bf16*)(ws + WS_WIHP);
    __bf16* Whhb  = (__bf16*)(ws + WS_WHHB);
    float*  zbuf  = (float*) (ws + WS_Z);
    float*  out   = (float*)d_out;

    (void)hipFuncSetAttribute((const void*)flash_kernel,
                              hipFuncAttributeMaxDynamicSharedMemorySize, 73984);

    enc_kernel<<<4, 256, 0, stream>>>(obs, pa, pr, ew1, eb1, ew2, eb2, out + OUT_FEATS, Xp);
    conv_all<<<CV_ALL, 256, 0, stream>>>(keys, cue, vals, w_hh, h0, w_ih,
                                         Kb, knrm, Qb, qq, Vt, Whhb, Hb, Wihp);
    flash_kernel<<<512, 256, 73984, stream>>>(Kb, Vt, Qb, qq, knrm, Opart, Lpart);
    combine_kernel<<<dim3(32, 8), 256, 0, stream>>>(Opart, Lpart, mt);
    lstm_gemm<<<dim3(16, 40), 256, 0, stream>>>(Xp, Wihp, Hb, Whhb, b_ih, b_hh, zbuf);
    gates_kernel<<<1024, 256, 0, stream>>>(zbuf, c0, mt, aw, ab, cw, cb, out);
}

// Round 16
// 371.350 us; speedup vs baseline: 1.2175x; 1.2175x over previous
//
#include <hip/hip_runtime.h>
#include <hip/hip_fp8.h>

typedef __bf16 bf16x8 __attribute__((ext_vector_type(8)));
typedef float  f32x4  __attribute__((ext_vector_type(4)));

#define NMEM_   65536
#define NCHUNK_ 16
#define NKC_    (NMEM_/NCHUNK_)   /* 4096 keys per chunk */
#define XPD_    160               /* padded DIN (133 -> 160) */

/* workspace byte offsets (all 4KB-aligned) */
#define WS_KB    ((size_t)0)           /* keys FP8 SWIZZLED [65536][512B] 33.5MB */
#define WS_VT    ((size_t)67108864)    /* vals^T FP8 x16 [512][65536B] 33.5MB */
#define WS_KNRM  ((size_t)134217728)   /* ||k||^2 f32 [65536]       */
#define WS_QB    ((size_t)134479872)   /* cue FP8 linear [1024][512B]   */
#define WS_QQ    ((size_t)135528448)   /* ||q||^2 f32 [1024]        */
#define WS_OP    ((size_t)135532544)   /* O partials f32 [16][16][512][64] 33.6MB */
#define WS_LP    ((size_t)169086976)   /* L partials f32 [16][1024]  */
#define WS_MT    ((size_t)169152512)   /* m_t f32 [1024][512]        */
#define WS_XP    ((size_t)171249664)   /* x_t bf16 padded [1024][160]*/
#define WS_HB    ((size_t)171577344)   /* h0 bf16 [1024][512]        */
#define WS_WIHP  ((size_t)172625920)   /* w_ih bf16 padded [2560][160]*/
#define WS_WHHB  ((size_t)173445120)   /* w_hh bf16 [2560][512]      */
#define WS_Z     ((size_t)176066560)   /* z f32 [1024][2560]         */

/* output float offsets */
#define OUT_LOG   0
#define OUT_VAL   4096
#define OUT_H     5120
#define OUT_C     529408
#define OUT_FEATS 1053696

__device__ __forceinline__ void gload16(const void* g, void* l) {
    __builtin_amdgcn_global_load_lds(
        (const __attribute__((address_space(1))) void*)g,
        (__attribute__((address_space(3))) void*)l, 16, 0, 0);
}

__device__ __forceinline__ unsigned char to_fp8(float f) {
    __hip_fp8_e4m3 v(f);
    return *(unsigned char*)&v;
}

/* 8 packed fp8 e4m3 -> bf16x8. HW cvt path when available; exact bit-trick
 * fallback (denormal-correct: f32 denormal x 2^120 is exact). */
__device__ __forceinline__ bf16x8 fp8x8_bf16(long v) {
    union { long l; unsigned int w[2]; } u; u.l = v;
    bf16x8 o;
#if __has_builtin(__builtin_amdgcn_cvt_f32_fp8)
    #pragma unroll
    for (int h = 0; h < 2; h++) {
        o[h*4+0] = (__bf16)__builtin_amdgcn_cvt_f32_fp8(u.w[h], 0);
        o[h*4+1] = (__bf16)__builtin_amdgcn_cvt_f32_fp8(u.w[h], 1);
        o[h*4+2] = (__bf16)__builtin_amdgcn_cvt_f32_fp8(u.w[h], 2);
        o[h*4+3] = (__bf16)__builtin_amdgcn_cvt_f32_fp8(u.w[h], 3);
    }
#else
    #pragma unroll
    for (int i = 0; i < 8; i++) {
        unsigned int b = (u.w[i>>2] >> ((i & 3) * 8)) & 0xffu;
        unsigned int t = ((b & 0x7fu) << 20) | ((b & 0x80u) << 24);
        float f; __builtin_memcpy(&f, &t, 4);
        o[i] = (__bf16)(f * 0x1p120f);
    }
#endif
    return o;
}

/* ---------------- encoder MLP + x_t assembly ---------------- */
__global__ __launch_bounds__(256) void enc_kernel(
    const float* __restrict__ obs, const float* __restrict__ pa, const float* __restrict__ pr,
    const float* __restrict__ w1, const float* __restrict__ b1,
    const float* __restrict__ w2, const float* __restrict__ b2,
    float* __restrict__ feats_out, __bf16* __restrict__ xp)
{
    __shared__ float W1s[64*9];
    __shared__ float B1s[64];
    __shared__ float W2s[128*64];
    __shared__ float B2s[128];
    int t = threadIdx.x;
    for (int i = t; i < 64*9;   i += 256) W1s[i] = w1[i];
    for (int i = t; i < 64;     i += 256) B1s[i] = b1[i];
    for (int i = t; i < 128*64; i += 256) W2s[i] = w2[i];
    for (int i = t; i < 128;    i += 256) B2s[i] = b2[i];
    __syncthreads();
    int row = blockIdx.x * 256 + t;
    float ob[9];
    #pragma unroll
    for (int j = 0; j < 9; j++) ob[j] = obs[row*9 + j];
    float h1[64];
    #pragma unroll 4
    for (int i = 0; i < 64; i++) {
        float a = B1s[i];
        #pragma unroll
        for (int j = 0; j < 9; j++) a += ob[j] * W1s[i*9 + j];
        h1[i] = fmaxf(a, 0.f);
    }
    for (int j = 0; j < 128; j += 4) {
        float a0 = B2s[j], a1 = B2s[j+1], a2 = B2s[j+2], a3 = B2s[j+3];
        for (int i = 0; i < 64; i++) {
            float h = h1[i];
            a0 += h * W2s[(j+0)*64 + i];
            a1 += h * W2s[(j+1)*64 + i];
            a2 += h * W2s[(j+2)*64 + i];
            a3 += h * W2s[(j+3)*64 + i];
        }
        a0 = fmaxf(a0,0.f); a1 = fmaxf(a1,0.f); a2 = fmaxf(a2,0.f); a3 = fmaxf(a3,0.f);
        feats_out[row*128 + j+0] = a0; feats_out[row*128 + j+1] = a1;
        feats_out[row*128 + j+2] = a2; feats_out[row*128 + j+3] = a3;
        xp[row*XPD_ + j+0] = (__bf16)a0; xp[row*XPD_ + j+1] = (__bf16)a1;
        xp[row*XPD_ + j+2] = (__bf16)a2; xp[row*XPD_ + j+3] = (__bf16)a3;
    }
    #pragma unroll
    for (int k = 0; k < 4; k++) xp[row*XPD_ + 128 + k] = (__bf16)pa[row*4 + k];
    xp[row*XPD_ + 132] = (__bf16)pr[row];
    #pragma unroll
    for (int c = 133; c < 160; c++) xp[row*XPD_ + c] = (__bf16)0.f;
}

/* ---------------- fused conversion kernel ----------------
 * keys/cue -> FP8 e4m3; vals^T -> FP8 e4m3 scaled x16 (descaled in combine).
 * keys swizzled for 8B ds_reads: byte c of row at c ^ ((row&15)<<3). */
#define CV_KEYS 16384
#define CV_CUE  (CV_KEYS + 256)
#define CV_VT   (CV_CUE + 8192)
#define CM_N1 (2560*512)
#define CM_N2 (1024*512)
#define CM_N3 (2560*160)
#define CV_ALL  (CV_VT + (CM_N1 + CM_N2 + CM_N3 + 255)/256)

__global__ __launch_bounds__(256) void conv_all(
    const float* __restrict__ keys, const float* __restrict__ cue,
    const float* __restrict__ vals,
    const float* __restrict__ whh, const float* __restrict__ h0,
    const float* __restrict__ wih,
    unsigned char* __restrict__ Kb, float* __restrict__ knrm,
    unsigned char* __restrict__ Qb, float* __restrict__ qq,
    unsigned char* __restrict__ Vt,
    __bf16* __restrict__ Whhb, __bf16* __restrict__ Hb, __bf16* __restrict__ Wihp)
{
    int bid = blockIdx.x;
    if (bid < CV_CUE) {
        const float* src; unsigned char* dst; float* nrm; int swz, rbase;
        if (bid < CV_KEYS) { src = keys; dst = Kb; nrm = knrm; swz = 1; rbase = bid*4; }
        else               { src = cue;  dst = Qb; nrm = qq;  swz = 0; rbase = (bid-CV_KEYS)*4; }
        int row  = rbase + (threadIdx.x >> 6);
        int lane = threadIdx.x & 63;
        const float* s = src + (size_t)row * 512 + lane * 8;
        float4 v0 = *(const float4*)s;
        float4 v1 = *(const float4*)(s + 4);
        float ss = v0.x*v0.x + v0.y*v0.y + v0.z*v0.z + v0.w*v0.w
                 + v1.x*v1.x + v1.y*v1.y + v1.z*v1.z + v1.w*v1.w;
        union { unsigned char b[8]; long v; } pk;
        pk.b[0] = to_fp8(v0.x); pk.b[1] = to_fp8(v0.y);
        pk.b[2] = to_fp8(v0.z); pk.b[3] = to_fp8(v0.w);
        pk.b[4] = to_fp8(v1.x); pk.b[5] = to_fp8(v1.y);
        pk.b[6] = to_fp8(v1.z); pk.b[7] = to_fp8(v1.w);
        int c = lane * 8;
        int addr = swz ? (c ^ ((row & 15) << 3)) : c;
        *(long*)(dst + (size_t)row * 512 + addr) = pk.v;
        #pragma unroll
        for (int m = 1; m < 64; m <<= 1) ss += __shfl_xor(ss, m, 64);
        if (lane == 0) nrm[row] = ss;
        return;
    }
    if (bid < CV_VT) {
        __shared__ float Ls[64*65];
        int local = bid - CV_CUE;
        int k0 = (local & 1023) * 64, d0 = (local >> 10) * 64;
        int rr = threadIdx.x >> 6, cc = threadIdx.x & 63;
        #pragma unroll
        for (int i = 0; i < 16; i++) {
            int row = i*4 + rr;
            Ls[row*65 + cc] = vals[(size_t)(k0 + row) * 512 + d0 + cc];
        }
        __syncthreads();
        #pragma unroll
        for (int i = 0; i < 16; i++) {
            int drow = i*4 + rr;
            Vt[(size_t)(d0 + drow) * 65536 + k0 + cc] = to_fp8(Ls[cc*65 + drow] * 16.f);
        }
        return;
    }
    {
        int i = (bid - CV_VT) * 256 + threadIdx.x;
        if (i < CM_N1) { Whhb[i] = (__bf16)whh[i]; return; }
        i -= CM_N1;
        if (i < CM_N2) { Hb[i] = (__bf16)h0[i]; return; }
        i -= CM_N2;
        if (i < CM_N3) {
            int r = i / 160, c = i - r * 160;
            Wihp[i] = (c < 133) ? (__bf16)wih[r*133 + c] : (__bf16)0.f;
        }
    }
}

/* ---------------- DND flash kernel (= R14 best: FP8 K + FP8 V) ----------
 * QK(t) || PV(t-1), 1 barrier/tile, counted vmcnt, no vmcnt(0) in loop.
 * fp8 K LDS-staged (swizzled <<3), fp8 V x16 reg-loaded + converted,
 * bf16 PV, P dbuf swizzled.  512 thr / 8 waves / 64 q-rows, grid 256.
 * Measured: flash 231us, MFMA 24.5%, conflicts 1K, FETCH 35.3MB. */
__global__ __launch_bounds__(512) void flash_kernel(
    const unsigned char* __restrict__ Kb, const unsigned char* __restrict__ Vt,
    const unsigned char* __restrict__ Qb, const float* __restrict__ qq,
    const float* __restrict__ knrm,
    float* __restrict__ Opart, float* __restrict__ Lpart)
{
    extern __shared__ char smem[];
    char*  KL  = smem;                       /* [2][32KB] fp8 K tiles (swizzled)*/
    char*  Plb = smem + 65536;               /* [2][64 q][128B] P dbuf swizzled */
    float* Lb  = (float*)(smem + 81920);     /* [64 q][2 wk]                    */

    const int tid = threadIdx.x, lane = tid & 63, w = tid >> 6;
    const int wq = w >> 1, wk = w & 1;
    const int lr = lane & 15, lq = lane >> 4;
    const int chunk = blockIdx.x & 15, qt = blockIdx.x >> 4;
    const int q0 = qt * 64, key0 = chunk * NKC_;

    /* Q fp8 fragments in registers: row=lr, 8 k-bytes at ks*32+lq*8. 32 VGPR */
    long qA[16];
    #pragma unroll
    for (int ks = 0; ks < 16; ks++)
        qA[ks] = *(const long*)(Qb + (size_t)(q0 + wq*16 + lr)*512 + ks*32 + lq*8);
    float qq4[4];
    #pragma unroll
    for (int r = 0; r < 4; r++)
        qq4[r] = qq[q0 + wq*16 + lq*4 + r];

    const float*         knp  = knrm + key0 + wk*32 + lr;
    const unsigned char* vrow = Vt + (size_t)(w*64 + lr)*65536 + key0 + lq*8;
    const char*          kg   = (const char*)Kb + (size_t)key0 * 512;

    /* prologue: stage fp8 K tile 0 (32KB = 4 x 16B/thread), drain, barrier */
    #pragma unroll
    for (int r = 0; r < 4; ++r)
        gload16(kg + r*8192 + tid*16, KL + r*8192 + tid*16);
    asm volatile("s_waitcnt vmcnt(0)" ::: "memory");
    __builtin_amdgcn_s_barrier();

    f32x4 oacc[4][4] = {};            /* O^T frags: [mf d][f2 q] = 64 acc regs */
    float lsum[4] = {};
    int cur = 0;
    const int kxor = lr << 3;

    #pragma unroll 1
    for (int t = 0; t < 64; ++t) {
        /* ---- issues: kn(2), V-raw(8) for tile t-1, stage-next(4) = 14 vmem ---- */
        float kn0 = knp[t*64];
        float kn1 = knp[t*64 + 16];
        const unsigned char* vb = vrow + ((t + 63) & 63) * 64;   /* V of tile t-1 */
        long vr[2][4];
        #pragma unroll
        for (int k2 = 0; k2 < 2; ++k2)
            #pragma unroll
            for (int mf = 0; mf < 4; ++mf)
                vr[k2][mf] = *(const long*)(vb + k2*32 + (size_t)mf*1048576);
        {   /* stage tile (t+1)&63 (wrap keeps vmcnt count uniform) */
            const char* src = kg + (size_t)((t+1)&63)*32768;
            char* dst = KL + (cur^1)*32768;
            #pragma unroll
            for (int r = 0; r < 4; ++r)
                gload16(src + r*8192 + tid*16, dst + r*8192 + tid*16);
        }
        /* own stage(t) done (14 = ops issued this iter) + own SM(t-1)
         * ds_writes drained; barrier makes it true block-wide.
         * stage(t+1)/vr/kn remain in flight. */
        asm volatile("s_waitcnt vmcnt(14) lgkmcnt(0)" ::: "memory");
        __builtin_amdgcn_sched_barrier(0);
        __builtin_amdgcn_s_barrier();
        /* ---- QK(t): S[16q x 32k], contraction 512, fp8 ---- */
        const char* kl = KL + cur*32768 + (wk*32 + lr)*512;
        f32x4 s0 = {0.f,0.f,0.f,0.f}, s1 = {0.f,0.f,0.f,0.f};
        __builtin_amdgcn_s_setprio(1);
        #pragma unroll
        for (int ks = 0; ks < 16; ++ks) {
            int off = (ks*32 + lq*8) ^ kxor;
            long kf0 = *(const long*)(kl + off);
            long kf1 = *(const long*)(kl + 8192 + off);
            s0 = __builtin_amdgcn_mfma_f32_16x16x32_fp8_fp8(qA[ks], kf0, s0, 0, 0, 0);
            s1 = __builtin_amdgcn_mfma_f32_16x16x32_fp8_fp8(qA[ks], kf1, s1, 0, 0, 0);
        }
        /* ---- PV(t-1): convert V fp8->bf16, O^T += V^T * P ---- */
        if (t) {
            const char* pb_ = Plb + ((t+1)&1)*8192;
            bf16x8 vc[2][4];
            #pragma unroll
            for (int k2 = 0; k2 < 2; ++k2)
                #pragma unroll
                for (int mf = 0; mf < 4; ++mf)
                    vc[k2][mf] = fp8x8_bf16(vr[k2][mf]);
            #pragma unroll
            for (int k2 = 0; k2 < 2; ++k2)
                #pragma unroll
                for (int f2 = 0; f2 < 4; ++f2) {
                    bf16x8 pf = *(const bf16x8*)(pb_ + (f2*16 + lr)*128
                                 + ((k2*64 + lq*16) ^ ((lr & 7) << 4)));
                    #pragma unroll
                    for (int mf = 0; mf < 4; ++mf)
                        oacc[mf][f2] = __builtin_amdgcn_mfma_f32_16x16x32_bf16(
                            vc[k2][mf], pf, oacc[mf][f2], 0, 0, 0);
                }
        }
        __builtin_amdgcn_s_setprio(0);
        /* ---- SM(t): softmax numerator + P[t&1] write (swizzled) ---- */
        char* pw = Plb + (t&1)*8192;
        #pragma unroll
        for (int r = 0; r < 4; ++r) {
            float d20 = fmaxf(qq4[r] + kn0 - 2.f*s0[r], 1e-12f);
            float d21 = fmaxf(qq4[r] + kn1 - 2.f*s1[r], 1e-12f);
            float p0 = __expf(-__builtin_amdgcn_sqrtf(d20));
            float p1 = __expf(-__builtin_amdgcn_sqrtf(d21));
            lsum[r] += p0 + p1;
            int row_ = wq*16 + lq*4 + r;
            int sw = (row_ & 7) << 4;
            *(__bf16*)(pw + row_*128 + (((wk*32 + lr)*2     ) ^ sw)) = (__bf16)p0;
            *(__bf16*)(pw + row_*128 + (((wk*32 + lr)*2 + 32) ^ sw)) = (__bf16)p1;
        }
        cur ^= 1;
    }

    /* ---- epilogue: PV(63), P buf 1 ---- */
    {
        const unsigned char* vb = vrow + 63*64;
        bf16x8 vc[2][4];
        #pragma unroll
        for (int k2 = 0; k2 < 2; ++k2)
            #pragma unroll
            for (int mf = 0; mf < 4; ++mf)
                vc[k2][mf] = fp8x8_bf16(*(const long*)(vb + k2*32 + (size_t)mf*1048576));
        asm volatile("s_waitcnt lgkmcnt(0)" ::: "memory");
        __builtin_amdgcn_sched_barrier(0);
        __builtin_amdgcn_s_barrier();              /* P[1] ready block-wide */
        const char* pb_ = Plb + 8192;
        #pragma unroll
        for (int k2 = 0; k2 < 2; ++k2)
            #pragma unroll
            for (int f2 = 0; f2 < 4; ++f2) {
                bf16x8 pf = *(const bf16x8*)(pb_ + (f2*16 + lr)*128
                             + ((k2*64 + lq*16) ^ ((lr & 7) << 4)));
                #pragma unroll
                for (int mf = 0; mf < 4; ++mf)
                    oacc[mf][f2] = __builtin_amdgcn_mfma_f32_16x16x32_bf16(
                        vc[k2][mf], pf, oacc[mf][f2], 0, 0, 0);
            }
    }
    asm volatile("s_waitcnt vmcnt(0)" ::: "memory");  /* drain wrap-stage DMA */

    /* O partials: layout [(chunk*16+qt)*512 + d][64 ql] */
    const size_t obase = (size_t)((chunk*16 + qt)*512) * 64;
    #pragma unroll
    for (int mf = 0; mf < 4; ++mf)
        #pragma unroll
        for (int f2 = 0; f2 < 4; ++f2)
            #pragma unroll
            for (int r = 0; r < 4; ++r) {
                int d = w*64 + mf*16 + lq*4 + r;
                Opart[obase + (size_t)d*64 + f2*16 + lr] = oacc[mf][f2][r];
            }
    #pragma unroll
    for (int r = 0; r < 4; ++r) {
        float s = lsum[r];
        s += __shfl_xor(s, 1, 64); s += __shfl_xor(s, 2, 64);
        s += __shfl_xor(s, 4, 64); s += __shfl_xor(s, 8, 64);
        if (lr == 0) Lb[(wq*16 + lq*4 + r)*2 + wk] = s;
    }
    __syncthreads();
    if (tid < 64)
        Lpart[chunk*1024 + q0 + tid] = Lb[tid*2] + Lb[tid*2 + 1];
}

/* ---------------- combine split-K partials -> m_t ----------------
 * Ls includes the 1/16 descale of the fp8 V encoding. */
__global__ __launch_bounds__(256) void combine_kernel(
    const float* __restrict__ Opart, const float* __restrict__ Lpart,
    float* __restrict__ mt)
{
    __shared__ float Ts[64*65];
    __shared__ float Ls[64];
    int qt = blockIdx.x, db = blockIdx.y * 64, t = threadIdx.x;
    float acc[16] = {};
    for (int c = 0; c < NCHUNK_; c++) {
        size_t base = (size_t)((c*16 + qt)*512 + db) * 64;
        #pragma unroll
        for (int i = 0; i < 16; i++) acc[i] += Opart[base + t + 256*i];
    }
    if (t < 64) {
        float s = 0.f;
        for (int c = 0; c < NCHUNK_; c++) s += Lpart[c*1024 + qt*64 + t];
        Ls[t] = 1.f / (s * 16.f);
    }
    #pragma unroll
    for (int i = 0; i < 16; i++) {
        int idx = t + 256*i;
        Ts[(idx >> 6)*65 + (idx & 63)] = acc[i];
    }
    __syncthreads();
    #pragma unroll
    for (int i = 0; i < 16; i++) {
        int widx = t + 256*i;
        int dloc = widx & 63, ql = widx >> 6;
        mt[(size_t)(qt*64 + ql)*512 + db + dloc] = Ts[dloc*65 + ql] * Ls[ql];
    }
}

/* ---------------- LSTM pre-activation GEMM: z = Xp@Wih^T + H@Whh^T + b ---------------- */
__global__ __launch_bounds__(256) void lstm_gemm(
    const __bf16* __restrict__ X,  const __bf16* __restrict__ Wx,
    const __bf16* __restrict__ Hb, const __bf16* __restrict__ Wh,
    const float* __restrict__ bi,  const float* __restrict__ bh,
    float* __restrict__ z)
{
    int tid = threadIdx.x, lane = tid & 63, w = tid >> 6;
    int wr = w >> 1, wc = w & 1;
    int lr = lane & 15, lq = lane >> 4;
    int q0 = blockIdx.x * 64, n0 = blockIdx.y * 64;
    f32x4 acc00 = {}, acc01 = {}, acc10 = {}, acc11 = {};
    #pragma unroll
    for (int ks = 0; ks < 5; ks++) {                       /* X part, K=160 */
        bf16x8 a0 = *(const bf16x8*)(X  + (size_t)(q0 + wr*32      + lr)*XPD_ + ks*32 + lq*8);
        bf16x8 a1 = *(const bf16x8*)(X  + (size_t)(q0 + wr*32 + 16 + lr)*XPD_ + ks*32 + lq*8);
        bf16x8 b0 = *(const bf16x8*)(Wx + (size_t)(n0 + wc*32      + lr)*XPD_ + ks*32 + lq*8);
        bf16x8 b1 = *(const bf16x8*)(Wx + (size_t)(n0 + wc*32 + 16 + lr)*XPD_ + ks*32 + lq*8);
        acc00 = __builtin_amdgcn_mfma_f32_16x16x32_bf16(a0, b0, acc00, 0,0,0);
        acc01 = __builtin_amdgcn_mfma_f32_16x16x32_bf16(a0, b1, acc01, 0,0,0);
        acc10 = __builtin_amdgcn_mfma_f32_16x16x32_bf16(a1, b0, acc10, 0,0,0);
        acc11 = __builtin_amdgcn_mfma_f32_16x16x32_bf16(a1, b1, acc11, 0,0,0);
    }
    #pragma unroll
    for (int ks = 0; ks < 16; ks++) {                      /* H part, K=512 */
        bf16x8 a0 = *(const bf16x8*)(Hb + (size_t)(q0 + wr*32      + lr)*512 + ks*32 + lq*8);
        bf16x8 a1 = *(const bf16x8*)(Hb + (size_t)(q0 + wr*32 + 16 + lr)*512 + ks*32 + lq*8);
        bf16x8 b0 = *(const bf16x8*)(Wh + (size_t)(n0 + wc*32      + lr)*512 + ks*32 + lq*8);
        bf16x8 b1 = *(const bf16x8*)(Wh + (size_t)(n0 + wc*32 + 16 + lr)*512 + ks*32 + lq*8);
        acc00 = __builtin_amdgcn_mfma_f32_16x16x32_bf16(a0, b0, acc00, 0,0,0);
        acc01 = __builtin_amdgcn_mfma_f32_16x16x32_bf16(a0, b1, acc01, 0,0,0);
        acc10 = __builtin_amdgcn_mfma_f32_16x16x32_bf16(a1, b0, acc10, 0,0,0);
        acc11 = __builtin_amdgcn_mfma_f32_16x16x32_bf16(a1, b1, acc11, 0,0,0);
    }
    int nA = n0 + wc*32 + lr, nB = nA + 16;
    float biasA = bi[nA] + bh[nA], biasB = bi[nB] + bh[nB];
    #pragma unroll
    for (int r = 0; r < 4; r++) {
        int qa = q0 + wr*32 + lq*4 + r, qb = qa + 16;
        z[(size_t)qa*2560 + nA] = acc00[r] + biasA;
        z[(size_t)qa*2560 + nB] = acc01[r] + biasB;
        z[(size_t)qb*2560 + nA] = acc10[r] + biasA;
        z[(size_t)qb*2560 + nB] = acc11[r] + biasB;
    }
}

/* ---------------- gates + heads ---------------- */
__global__ __launch_bounds__(256) void gates_kernel(
    const float* __restrict__ z,  const float* __restrict__ c0, const float* __restrict__ mt,
    const float* __restrict__ aw, const float* __restrict__ ab,
    const float* __restrict__ cw, const float* __restrict__ cb,
    float* __restrict__ out)
{
    __shared__ float hrow[512];
    __shared__ float red[256];
    int q = blockIdx.x, t = threadIdx.x;
    const float* zq = z + (size_t)q * 2560;
    for (int d = t; d < 512; d += 256) {
        float zi = zq[d], zf = zq[512 + d], zg = zq[1024 + d], zo = zq[1536 + d], zr = zq[2048 + d];
        float ig = 1.f / (1.f + __expf(-zi));
        float fg = 1.f / (1.f + __expf(-zf));
        float gg = tanhf(zg);
        float og = 1.f / (1.f + __expf(-zo));
        float rg = 1.f / (1.f + __expf(-zr));
        float cn = fg * c0[(size_t)q*512 + d] + ig * gg + rg * mt[(size_t)q*512 + d];
        float hn = og * tanhf(cn);
        out[OUT_H + (size_t)q*512 + d] = hn;
        out[OUT_C + (size_t)q*512 + d] = cn;
        hrow[d] = hn;
    }
    __syncthreads();
    for (int o = 0; o < 5; o++) {
        const float* wv = (o < 4) ? (aw + o*512) : cw;
        float p = 0.f;
        for (int d = t; d < 512; d += 256) p += hrow[d] * wv[d];
        red[t] = p;
        __syncthreads();
        for (int s = 128; s > 0; s >>= 1) {
            if (t < s) red[t] += red[t + s];
            __syncthreads();
        }
        if (t == 0) {
            float v = red[0] + ((o < 4) ? ab[o] : cb[0]);
            if (o < 4) out[OUT_LOG + q*4 + o] = v;
            else       out[OUT_VAL + q] = v;
        }
        __syncthreads();
    }
}

extern "C" void kernel_launch(void* const* d_in, const int* in_sizes, int n_in,
                              void* d_out, int out_size, void* d_ws, size_t ws_size,
                              hipStream_t stream) {
    (void)in_sizes; (void)n_in; (void)out_size; (void)ws_size;
    const float* obs   = (const float*)d_in[0];
    const float* pa    = (const float*)d_in[1];
    const float* pr    = (const float*)d_in[2];
    const float* h0    = (const float*)d_in[3];
    const float* c0    = (const float*)d_in[4];
    const float* cue   = (const float*)d_in[5];
    const float* ew1   = (const float*)d_in[6];
    const float* eb1   = (const float*)d_in[7];
    const float* ew2   = (const float*)d_in[8];
    const float* eb2   = (const float*)d_in[9];
    const float* w_ih  = (const float*)d_in[10];
    const float* w_hh  = (const float*)d_in[11];
    const float* b_ih  = (const float*)d_in[12];
    const float* b_hh  = (const float*)d_in[13];
    const float* aw    = (const float*)d_in[14];
    const float* ab    = (const float*)d_in[15];
    const float* cw    = (const float*)d_in[16];
    const float* cb    = (const float*)d_in[17];
    const float* keys  = (const float*)d_in[18];
    const float* vals  = (const float*)d_in[19];

    char* ws = (char*)d_ws;
    unsigned char* Kb = (unsigned char*)(ws + WS_KB);
    unsigned char* Vt = (unsigned char*)(ws + WS_VT);
    float*  knrm  = (float*) (ws + WS_KNRM);
    unsigned char* Qb = (unsigned char*)(ws + WS_QB);
    float*  qq    = (float*) (ws + WS_QQ);
    float*  Opart = (float*) (ws + WS_OP);
    float*  Lpart = (float*) (ws + WS_LP);
    float*  mt    = (float*) (ws + WS_MT);
    __bf16* Xp    = (__bf16*)(ws + WS_XP);
    __bf16* Hb    = (__bf16*)(ws + WS_HB);
    __bf16* Wihp  = (__bf16*)(ws + WS_WIHP);
    __bf16* Whhb  = (__bf16*)(ws + WS_WHHB);
    float*  zbuf  = (float*) (ws + WS_Z);
    float*  out   = (float*)d_out;

    (void)hipFuncSetAttribute((const void*)flash_kernel,
                              hipFuncAttributeMaxDynamicSharedMemorySize, 82432);

    enc_kernel<<<4, 256, 0, stream>>>(obs, pa, pr, ew1, eb1, ew2, eb2, out + OUT_FEATS, Xp);
    conv_all<<<CV_ALL, 256, 0, stream>>>(keys, cue, vals, w_hh, h0, w_ih,
                                         Kb, knrm, Qb, qq, Vt, Whhb, Hb, Wihp);
    flash_kernel<<<256, 512, 82432, stream>>>(Kb, Vt, Qb, qq, knrm, Opart, Lpart);
    combine_kernel<<<dim3(16, 8), 256, 0, stream>>>(Opart, Lpart, mt);
    lstm_gemm<<<dim3(16, 40), 256, 0, stream>>>(Xp, Wihp, Hb, Whhb, b_ih, b_hh, zbuf);
    gates_kernel<<<1024, 256, 0, stream>>>(zbuf, c0, mt, aw, ab, cw, cb, out);
}